// Round 2
// baseline (145.066 us; speedup 1.0000x reference)
//
#include <hip/hip_runtime.h>
#include <hip/hip_fp16.h>
#include <math.h>

#define BB 16
#define CC 3
#define HH 512
#define WW 512
#define HW (HH * WW)
#define KW 11
#define RAD 5

// ---------------- Kernel 1: horizontal pass (one wave per row) ----------------
// LDS skewed index: s in [0, 522), idx = s + (s>>3)  -> stride-9 across lanes,
// conflict-free for both the j-write and k-read patterns.
#define SIDX(s) ((s) + ((s) >> 3))
#define SBUF 592

__global__ __launch_bounds__(256) void k1_hpass(
    const float* __restrict__ pred, const float* __restrict__ target,
    __half2* __restrict__ hdot, __half2* __restrict__ hpp, __half2* __restrict__ htt,
    float* __restrict__ acc)
{
    __shared__ float sbuf[4][3][SBUF];
    const int tid = threadIdx.x;
    const int wave = tid >> 6, lane = tid & 63;
    const int row = blockIdx.x * 4 + wave;      // 0..8191
    const int b = row >> 9, y = row & 511;
    const long rbase = (long)b * (CC * HW) + (long)y * WW;
    const int c0 = lane * 8;

    // load 8 consecutive cols x 3 channels x 2 tensors, float4
    float p[3][8], t[3][8];
    #pragma unroll
    for (int ch = 0; ch < 3; ++ch) {
        const float* pp_ = pred + rbase + (long)ch * HW + c0;
        const float* tp_ = target + rbase + (long)ch * HW + c0;
        float4 a0 = *(const float4*)pp_;
        float4 a1 = *(const float4*)(pp_ + 4);
        float4 b0 = *(const float4*)tp_;
        float4 b1 = *(const float4*)(tp_ + 4);
        p[ch][0]=a0.x; p[ch][1]=a0.y; p[ch][2]=a0.z; p[ch][3]=a0.w;
        p[ch][4]=a1.x; p[ch][5]=a1.y; p[ch][6]=a1.z; p[ch][7]=a1.w;
        t[ch][0]=b0.x; t[ch][1]=b0.y; t[ch][2]=b0.z; t[ch][3]=b0.w;
        t[ch][4]=b1.x; t[ch][5]=b1.y; t[ch][6]=b1.z; t[ch][7]=b1.w;
    }

    float sq = 0.f;
    #pragma unroll
    for (int j = 0; j < 8; ++j) {
        const float dot = p[0][j]*t[0][j] + p[1][j]*t[1][j] + p[2][j]*t[2][j];
        const float pps = p[0][j]*p[0][j] + p[1][j]*p[1][j] + p[2][j]*p[2][j];
        const float tts = t[0][j]*t[0][j] + t[1][j]*t[1][j] + t[2][j]*t[2][j];
        const float e0 = p[0][j]-t[0][j], e1 = p[1][j]-t[1][j], e2 = p[2][j]-t[2][j];
        sq += e0*e0 + e1*e1 + e2*e2;
        const int idx = SIDX(c0 + j + RAD);
        sbuf[wave][0][idx] = dot;
        sbuf[wave][1][idx] = pps;
        sbuf[wave][2][idx] = tts;
    }
    // zero-pad edges: s in [0,5) and [517,522)
    if (lane < 5) {
        const int i0 = SIDX(lane);
        sbuf[wave][0][i0] = 0.f; sbuf[wave][1][i0] = 0.f; sbuf[wave][2][i0] = 0.f;
    } else if (lane < 10) {
        const int i1 = SIDX(512 + lane);
        sbuf[wave][0][i1] = 0.f; sbuf[wave][1][i1] = 0.f; sbuf[wave][2][i1] = 0.f;
    }
    __syncthreads();

    // sliding 11-window over 18 values -> 8 outputs
    float vd[18], vp[18], vt[18];
    #pragma unroll
    for (int k = 0; k < 18; ++k) {
        const int idx = SIDX(c0 + k);
        vd[k] = sbuf[wave][0][idx];
        vp[k] = sbuf[wave][1][idx];
        vt[k] = sbuf[wave][2][idx];
    }
    float wd[8], wp[8], wt[8];
    wd[0] = vd[0]; wp[0] = vp[0]; wt[0] = vt[0];
    #pragma unroll
    for (int k = 1; k < 11; ++k) { wd[0]+=vd[k]; wp[0]+=vp[k]; wt[0]+=vt[k]; }
    #pragma unroll
    for (int j = 1; j < 8; ++j) {
        wd[j] = wd[j-1] + vd[j+10] - vd[j-1];
        wp[j] = wp[j-1] + vp[j+10] - vp[j-1];
        wt[j] = wt[j-1] + vt[j+10] - vt[j-1];
    }

    const long obase = (long)row * (WW/2) + lane * 4;   // half2 units
    #pragma unroll
    for (int q = 0; q < 4; ++q) {
        hdot[obase + q] = __floats2half2_rn(wd[2*q], wd[2*q+1]);
        hpp [obase + q] = __floats2half2_rn(wp[2*q], wp[2*q+1]);
        htt [obase + q] = __floats2half2_rn(wt[2*q], wt[2*q+1]);
    }

    #pragma unroll
    for (int o = 32; o > 0; o >>= 1) sq += __shfl_down(sq, o);
    if (lane == 0) atomicAdd(&acc[b], sq);
}

// ---------------- Kernel 2: vertical pass + cosine ----------------
#define SEG 16
__global__ __launch_bounds__(256) void k2_vpass(
    const __half2* __restrict__ hdot, const __half2* __restrict__ hpp,
    const __half2* __restrict__ htt, float* __restrict__ acc)
{
    __shared__ float red[4];
    const int tid = threadIdx.x;
    const int b = blockIdx.x >> 5;
    const int seg = blockIdx.x & 31;
    const int y0 = seg * SEG;
    const long plane = (long)b * (HW / 2);

    float2 rd[11], rp[11], rt[11];
    float cosacc = 0.f;

    #pragma unroll
    for (int it = 0; it < SEG + 10; ++it) {
        const int y = y0 - RAD + it;
        float2 d = {0.f, 0.f}, pq = {0.f, 0.f}, tq = {0.f, 0.f};
        if (y >= 0 && y < HH) {
            const long off = plane + (long)y * (WW/2) + tid;
            d  = __half22float2(hdot[off]);
            pq = __half22float2(hpp[off]);
            tq = __half22float2(htt[off]);
        }
        rd[it % 11] = d; rp[it % 11] = pq; rt[it % 11] = tq;
        if (it >= 10) {
            float2 sd = rd[0], sp = rp[0], st = rt[0];
            #pragma unroll
            for (int k = 1; k < 11; ++k) {
                sd.x += rd[k].x; sd.y += rd[k].y;
                sp.x += rp[k].x; sp.y += rp[k].y;
                st.x += rt[k].x; st.y += rt[k].y;
            }
            cosacc += sd.x / (sqrtf(sp.x) * sqrtf(st.x) + 1e-6f);
            cosacc += sd.y / (sqrtf(sp.y) * sqrtf(st.y) + 1e-6f);
        }
    }

    #pragma unroll
    for (int o = 32; o > 0; o >>= 1) cosacc += __shfl_down(cosacc, o);
    const int wave = tid >> 6, lane = tid & 63;
    if (lane == 0) red[wave] = cosacc;
    __syncthreads();
    if (tid == 0)
        atomicAdd(&acc[BB], red[0] + red[1] + red[2] + red[3]);
}

// ---------------- finalize ----------------
__global__ void psnr_lcs_finalize(const float* __restrict__ acc,
                                  float* __restrict__ out)
{
    if (threadIdx.x == 0) {
        const float scale = 4.342944819032518f;   // 10 / ln(10)
        float s = 0.f;
        for (int b = 0; b < BB; ++b)
            s += logf(acc[b] / (float)(CC * HW) + 1e-8f);
        const float psnr = scale * (s / (float)BB);
        const float lcs  = 1.f - acc[BB] / (float)(BB * HW);
        out[0] = psnr + lcs;
    }
}

// ---------------- fallback fused kernel (R1) for small ws ----------------
#define TS 32
#define RS (TS + KW - 1)
__global__ __launch_bounds__(256) void psnr_lcs_fused(
    const float* __restrict__ pred, const float* __restrict__ target,
    float* __restrict__ acc)
{
    __shared__ float s_dot[RS][RS], s_pp[RS][RS], s_tt[RS][RS];
    __shared__ float h_dot[RS][TS], h_pp[RS][TS], h_tt[RS][TS];
    __shared__ float red[8];
    const int tid = threadIdx.x;
    const int bx = blockIdx.x, by = blockIdx.y, b = blockIdx.z;
    const long base = (long)b * CC * HW;
    for (int idx = tid; idx < RS * RS; idx += 256) {
        const int rr = idx / RS, cc = idx % RS;
        const int gy = by * TS + rr - RAD, gx = bx * TS + cc - RAD;
        float dot = 0.f, pp = 0.f, tt = 0.f;
        if (gx >= 0 && gx < WW && gy >= 0 && gy < HH) {
            const long off = base + (long)gy * WW + gx;
            const float p0 = pred[off], t0 = target[off];
            const float p1 = pred[off+HW], t1 = target[off+HW];
            const float p2 = pred[off+2*HW], t2 = target[off+2*HW];
            dot = p0*t0+p1*t1+p2*t2; pp = p0*p0+p1*p1+p2*p2; tt = t0*t0+t1*t1+t2*t2;
        }
        s_dot[rr][cc]=dot; s_pp[rr][cc]=pp; s_tt[rr][cc]=tt;
    }
    __syncthreads();
    for (int idx = tid; idx < RS * TS; idx += 256) {
        const int r = idx / TS, c = idx % TS;
        float sd=0.f, sp=0.f, st=0.f;
        #pragma unroll
        for (int dx = 0; dx < KW; ++dx) { sd+=s_dot[r][c+dx]; sp+=s_pp[r][c+dx]; st+=s_tt[r][c+dx]; }
        h_dot[r][c]=sd; h_pp[r][c]=sp; h_tt[r][c]=st;
    }
    __syncthreads();
    float cos_part = 0.f, sq_part = 0.f;
    const int oc = tid & 31, r0 = tid >> 5;
    #pragma unroll
    for (int k = 0; k < 4; ++k) {
        const int orow = r0 + k * 8;
        float sxy=0.f, sxx=0.f, syy=0.f;
        #pragma unroll
        for (int dy = 0; dy < KW; ++dy) { sxy+=h_dot[orow+dy][oc]; sxx+=h_pp[orow+dy][oc]; syy+=h_tt[orow+dy][oc]; }
        cos_part += sxy / (sqrtf(sxx)*sqrtf(syy) + 1e-6f);
        sq_part += s_pp[orow+RAD][oc+RAD] - 2.f*s_dot[orow+RAD][oc+RAD] + s_tt[orow+RAD][oc+RAD];
    }
    #pragma unroll
    for (int o = 32; o > 0; o >>= 1) { cos_part += __shfl_down(cos_part, o); sq_part += __shfl_down(sq_part, o); }
    const int wave = tid >> 6, lane = tid & 63;
    if (lane == 0) { red[wave] = cos_part; red[wave+4] = sq_part; }
    __syncthreads();
    if (tid == 0) {
        atomicAdd(&acc[b], red[4]+red[5]+red[6]+red[7]);
        atomicAdd(&acc[BB], red[0]+red[1]+red[2]+red[3]);
    }
}

extern "C" void kernel_launch(void* const* d_in, const int* in_sizes, int n_in,
                              void* d_out, int out_size, void* d_ws, size_t ws_size,
                              hipStream_t stream)
{
    const float* pred   = (const float*)d_in[0];
    const float* target = (const float*)d_in[1];
    float* acc = (float*)d_ws;

    const size_t map_bytes = (size_t)BB * HW * sizeof(__half);   // 8 MB per map
    const size_t need = 256 + 3 * map_bytes;

    hipMemsetAsync(acc, 0, (BB + 1) * sizeof(float), stream);

    if (ws_size >= need) {
        __half2* hdot = (__half2*)((char*)d_ws + 256);
        __half2* hpp  = (__half2*)((char*)d_ws + 256 + map_bytes);
        __half2* htt  = (__half2*)((char*)d_ws + 256 + 2 * map_bytes);
        k1_hpass<<<dim3(BB * HH / 4), 256, 0, stream>>>(pred, target, hdot, hpp, htt, acc);
        k2_vpass<<<dim3(BB * (HH / SEG)), 256, 0, stream>>>(hdot, hpp, htt, acc);
    } else {
        dim3 grid(WW / TS, HH / TS, BB);
        psnr_lcs_fused<<<grid, 256, 0, stream>>>(pred, target, acc);
    }
    psnr_lcs_finalize<<<1, 64, 0, stream>>>(acc, (float*)d_out);
}

// Round 3
// 46.314 us; speedup vs baseline: 3.1323x; 3.1323x over previous
//
#include <hip/hip_runtime.h>
#include <hip/hip_fp16.h>
#include <math.h>

#define BB 16
#define CC 3
#define HH 512
#define WW 512
#define HW (HH * WW)
#define KW 11
#define RAD 5

// ws layout: [0, 8KB) ws_sq (2048 f), [8KB, 10KB) ws_cos (512 f), maps from 16KB
#define WS_SQ_OFF   0
#define WS_COS_OFF  8192
#define WS_MAP_OFF  16384

union H2F { __half2 h; float f; };

// ---------------- Kernel 1: horizontal pass (one wave per row) ----------------
#define SIDX(s) ((s) + ((s) >> 3))
#define SBUF 592

__global__ __launch_bounds__(256) void k1_hpass(
    const float* __restrict__ pred, const float* __restrict__ target,
    __half2* __restrict__ hdot, __half2* __restrict__ hpp, __half2* __restrict__ htt,
    float* __restrict__ ws_sq)
{
    __shared__ float sbuf[4][3][SBUF];
    __shared__ float red[4];
    const int tid = threadIdx.x;
    const int wave = tid >> 6, lane = tid & 63;
    const int row = blockIdx.x * 4 + wave;      // 0..8191, 128 blocks per image
    const int b = row >> 9, y = row & 511;
    const long rbase = (long)b * (CC * HW) + (long)y * WW;
    const int c0 = lane * 8;

    float p[3][8], t[3][8];
    #pragma unroll
    for (int ch = 0; ch < 3; ++ch) {
        const float* pp_ = pred + rbase + (long)ch * HW + c0;
        const float* tp_ = target + rbase + (long)ch * HW + c0;
        float4 a0 = *(const float4*)pp_;
        float4 a1 = *(const float4*)(pp_ + 4);
        float4 b0 = *(const float4*)tp_;
        float4 b1 = *(const float4*)(tp_ + 4);
        p[ch][0]=a0.x; p[ch][1]=a0.y; p[ch][2]=a0.z; p[ch][3]=a0.w;
        p[ch][4]=a1.x; p[ch][5]=a1.y; p[ch][6]=a1.z; p[ch][7]=a1.w;
        t[ch][0]=b0.x; t[ch][1]=b0.y; t[ch][2]=b0.z; t[ch][3]=b0.w;
        t[ch][4]=b1.x; t[ch][5]=b1.y; t[ch][6]=b1.z; t[ch][7]=b1.w;
    }

    float sq = 0.f;
    #pragma unroll
    for (int j = 0; j < 8; ++j) {
        const float dot = p[0][j]*t[0][j] + p[1][j]*t[1][j] + p[2][j]*t[2][j];
        const float pps = p[0][j]*p[0][j] + p[1][j]*p[1][j] + p[2][j]*p[2][j];
        const float tts = t[0][j]*t[0][j] + t[1][j]*t[1][j] + t[2][j]*t[2][j];
        const float e0 = p[0][j]-t[0][j], e1 = p[1][j]-t[1][j], e2 = p[2][j]-t[2][j];
        sq += e0*e0 + e1*e1 + e2*e2;
        const int idx = SIDX(c0 + j + RAD);
        sbuf[wave][0][idx] = dot;
        sbuf[wave][1][idx] = pps;
        sbuf[wave][2][idx] = tts;
    }
    if (lane < 5) {
        const int i0 = SIDX(lane);
        sbuf[wave][0][i0] = 0.f; sbuf[wave][1][i0] = 0.f; sbuf[wave][2][i0] = 0.f;
    } else if (lane < 10) {
        const int i1 = SIDX(512 + lane);
        sbuf[wave][0][i1] = 0.f; sbuf[wave][1][i1] = 0.f; sbuf[wave][2][i1] = 0.f;
    }
    __syncthreads();

    float vd[18], vp[18], vt[18];
    #pragma unroll
    for (int k = 0; k < 18; ++k) {
        const int idx = SIDX(c0 + k);
        vd[k] = sbuf[wave][0][idx];
        vp[k] = sbuf[wave][1][idx];
        vt[k] = sbuf[wave][2][idx];
    }
    float wd[8], wp[8], wt[8];
    wd[0] = vd[0]; wp[0] = vp[0]; wt[0] = vt[0];
    #pragma unroll
    for (int k = 1; k < 11; ++k) { wd[0]+=vd[k]; wp[0]+=vp[k]; wt[0]+=vt[k]; }
    #pragma unroll
    for (int j = 1; j < 8; ++j) {
        wd[j] = wd[j-1] + vd[j+10] - vd[j-1];
        wp[j] = wp[j-1] + vp[j+10] - vp[j-1];
        wt[j] = wt[j-1] + vt[j+10] - vt[j-1];
    }

    // coalesced float4 (8 halfs) store per map
    const long obase = (long)row * (WW/2) + lane * 4;   // half2 units
    float4 od, op, ot;
    { H2F u; u.h = __floats2half2_rn(wd[0], wd[1]); od.x = u.f;
      u.h = __floats2half2_rn(wd[2], wd[3]); od.y = u.f;
      u.h = __floats2half2_rn(wd[4], wd[5]); od.z = u.f;
      u.h = __floats2half2_rn(wd[6], wd[7]); od.w = u.f; }
    { H2F u; u.h = __floats2half2_rn(wp[0], wp[1]); op.x = u.f;
      u.h = __floats2half2_rn(wp[2], wp[3]); op.y = u.f;
      u.h = __floats2half2_rn(wp[4], wp[5]); op.z = u.f;
      u.h = __floats2half2_rn(wp[6], wp[7]); op.w = u.f; }
    { H2F u; u.h = __floats2half2_rn(wt[0], wt[1]); ot.x = u.f;
      u.h = __floats2half2_rn(wt[2], wt[3]); ot.y = u.f;
      u.h = __floats2half2_rn(wt[4], wt[5]); ot.z = u.f;
      u.h = __floats2half2_rn(wt[6], wt[7]); ot.w = u.f; }
    *(float4*)&hdot[obase] = od;
    *(float4*)&hpp [obase] = op;
    *(float4*)&htt [obase] = ot;

    // block-level reduce of sq, single plain store (NO global atomics)
    #pragma unroll
    for (int o = 32; o > 0; o >>= 1) sq += __shfl_down(sq, o);
    if (lane == 0) red[wave] = sq;
    __syncthreads();
    if (tid == 0)
        ws_sq[blockIdx.x] = red[0] + red[1] + red[2] + red[3];
}

// ---------------- Kernel 2: vertical pass + cosine ----------------
#define SEG 16
__global__ __launch_bounds__(256) void k2_vpass(
    const __half2* __restrict__ hdot, const __half2* __restrict__ hpp,
    const __half2* __restrict__ htt, float* __restrict__ ws_cos)
{
    __shared__ float red[4];
    const int tid = threadIdx.x;
    const int b = blockIdx.x >> 5;
    const int seg = blockIdx.x & 31;
    const int y0 = seg * SEG;
    const long plane = (long)b * (HW / 2);

    float2 rd[11], rp[11], rt[11];
    float cosacc = 0.f;

    #pragma unroll
    for (int it = 0; it < SEG + 10; ++it) {
        const int y = y0 - RAD + it;
        float2 d = {0.f, 0.f}, pq = {0.f, 0.f}, tq = {0.f, 0.f};
        if (y >= 0 && y < HH) {
            const long off = plane + (long)y * (WW/2) + tid;
            d  = __half22float2(hdot[off]);
            pq = __half22float2(hpp[off]);
            tq = __half22float2(htt[off]);
        }
        rd[it % 11] = d; rp[it % 11] = pq; rt[it % 11] = tq;
        if (it >= 10) {
            float2 sd = rd[0], sp = rp[0], st = rt[0];
            #pragma unroll
            for (int k = 1; k < 11; ++k) {
                sd.x += rd[k].x; sd.y += rd[k].y;
                sp.x += rp[k].x; sp.y += rp[k].y;
                st.x += rt[k].x; st.y += rt[k].y;
            }
            cosacc += sd.x / (sqrtf(sp.x) * sqrtf(st.x) + 1e-6f);
            cosacc += sd.y / (sqrtf(sp.y) * sqrtf(st.y) + 1e-6f);
        }
    }

    #pragma unroll
    for (int o = 32; o > 0; o >>= 1) cosacc += __shfl_down(cosacc, o);
    const int wave = tid >> 6, lane = tid & 63;
    if (lane == 0) red[wave] = cosacc;
    __syncthreads();
    if (tid == 0)
        ws_cos[blockIdx.x] = red[0] + red[1] + red[2] + red[3];
}

// ---------------- finalize: reduce 2048 sq-partials + 512 cos-partials ----------------
__global__ __launch_bounds__(256) void finalize2(
    const float* __restrict__ ws_sq, const float* __restrict__ ws_cos,
    float* __restrict__ out)
{
    __shared__ float sq_b[16];
    __shared__ float cred[4];
    const int tid = threadIdx.x;

    // sq: 128 partials per image; 16 threads per image, 8 values each
    const int b = tid >> 4, j = tid & 15;
    float s = 0.f;
    #pragma unroll
    for (int k = 0; k < 8; ++k) s += ws_sq[b * 128 + j * 8 + k];
    #pragma unroll
    for (int o = 8; o > 0; o >>= 1) s += __shfl_down(s, o, 16);
    if (j == 0) sq_b[b] = s;

    // cos: 512 partials
    float c = ws_cos[tid] + ws_cos[tid + 256];
    #pragma unroll
    for (int o = 32; o > 0; o >>= 1) c += __shfl_down(c, o);
    if ((tid & 63) == 0) cred[tid >> 6] = c;
    __syncthreads();

    if (tid == 0) {
        const float csum = cred[0] + cred[1] + cred[2] + cred[3];
        const float scale = 4.342944819032518f;   // 10 / ln(10)
        float lsum = 0.f;
        for (int bb = 0; bb < 16; ++bb)
            lsum += logf(sq_b[bb] / (float)(CC * HW) + 1e-8f);
        out[0] = scale * (lsum / (float)BB) + (1.f - csum / (float)(BB * HW));
    }
}

// ---------------- fallback fused kernel (small ws): per-block partial stores ----------------
#define TS 32
#define RS (TS + KW - 1)
__global__ __launch_bounds__(256) void psnr_lcs_fused(
    const float* __restrict__ pred, const float* __restrict__ target,
    float* __restrict__ ws_sq, float* __restrict__ ws_cos)
{
    __shared__ float s_dot[RS][RS], s_pp[RS][RS], s_tt[RS][RS];
    __shared__ float h_dot[RS][TS], h_pp[RS][TS], h_tt[RS][TS];
    __shared__ float red[8];
    const int tid = threadIdx.x;
    const int bx = blockIdx.x, by = blockIdx.y, b = blockIdx.z;
    const long base = (long)b * CC * HW;
    for (int idx = tid; idx < RS * RS; idx += 256) {
        const int rr = idx / RS, cc = idx % RS;
        const int gy = by * TS + rr - RAD, gx = bx * TS + cc - RAD;
        float dot = 0.f, pp = 0.f, tt = 0.f;
        if (gx >= 0 && gx < WW && gy >= 0 && gy < HH) {
            const long off = base + (long)gy * WW + gx;
            const float p0 = pred[off], t0 = target[off];
            const float p1 = pred[off+HW], t1 = target[off+HW];
            const float p2 = pred[off+2*HW], t2 = target[off+2*HW];
            dot = p0*t0+p1*t1+p2*t2; pp = p0*p0+p1*p1+p2*p2; tt = t0*t0+t1*t1+t2*t2;
        }
        s_dot[rr][cc]=dot; s_pp[rr][cc]=pp; s_tt[rr][cc]=tt;
    }
    __syncthreads();
    for (int idx = tid; idx < RS * TS; idx += 256) {
        const int r = idx / TS, c = idx % TS;
        float sd=0.f, sp=0.f, st=0.f;
        #pragma unroll
        for (int dx = 0; dx < KW; ++dx) { sd+=s_dot[r][c+dx]; sp+=s_pp[r][c+dx]; st+=s_tt[r][c+dx]; }
        h_dot[r][c]=sd; h_pp[r][c]=sp; h_tt[r][c]=st;
    }
    __syncthreads();
    float cos_part = 0.f, sq_part = 0.f;
    const int oc = tid & 31, r0 = tid >> 5;
    #pragma unroll
    for (int k = 0; k < 4; ++k) {
        const int orow = r0 + k * 8;
        float sxy=0.f, sxx=0.f, syy=0.f;
        #pragma unroll
        for (int dy = 0; dy < KW; ++dy) { sxy+=h_dot[orow+dy][oc]; sxx+=h_pp[orow+dy][oc]; syy+=h_tt[orow+dy][oc]; }
        cos_part += sxy / (sqrtf(sxx)*sqrtf(syy) + 1e-6f);
        sq_part += s_pp[orow+RAD][oc+RAD] - 2.f*s_dot[orow+RAD][oc+RAD] + s_tt[orow+RAD][oc+RAD];
    }
    #pragma unroll
    for (int o = 32; o > 0; o >>= 1) { cos_part += __shfl_down(cos_part, o); sq_part += __shfl_down(sq_part, o); }
    const int wave = tid >> 6, lane = tid & 63;
    if (lane == 0) { red[wave] = cos_part; red[wave+4] = sq_part; }
    __syncthreads();
    if (tid == 0) {
        const int flat = (b * gridDim.y + by) * gridDim.x + bx;   // 0..4095
        ws_sq[flat]  = red[4]+red[5]+red[6]+red[7];
        ws_cos[flat] = red[0]+red[1]+red[2]+red[3];
    }
}

__global__ __launch_bounds__(256) void finalize_fb(
    const float* __restrict__ ws_sq, const float* __restrict__ ws_cos,
    float* __restrict__ out)
{
    __shared__ float sq_b[16];
    __shared__ float cred[4];
    const int tid = threadIdx.x;
    // 4096 partials, 256 per image; 16 threads per image, 16 values each
    const int b = tid >> 4, j = tid & 15;
    float s = 0.f, c = 0.f;
    #pragma unroll
    for (int k = 0; k < 16; ++k) {
        s += ws_sq[b * 256 + j * 16 + k];
        c += ws_cos[b * 256 + j * 16 + k];
    }
    #pragma unroll
    for (int o = 8; o > 0; o >>= 1) s += __shfl_down(s, o, 16);
    if (j == 0) sq_b[b] = s;
    #pragma unroll
    for (int o = 32; o > 0; o >>= 1) c += __shfl_down(c, o);
    if ((tid & 63) == 0) cred[tid >> 6] = c;
    __syncthreads();
    if (tid == 0) {
        const float csum = cred[0] + cred[1] + cred[2] + cred[3];
        const float scale = 4.342944819032518f;
        float lsum = 0.f;
        for (int bb = 0; bb < 16; ++bb)
            lsum += logf(sq_b[bb] / (float)(CC * HW) + 1e-8f);
        out[0] = scale * (lsum / (float)BB) + (1.f - csum / (float)(BB * HW));
    }
}

extern "C" void kernel_launch(void* const* d_in, const int* in_sizes, int n_in,
                              void* d_out, int out_size, void* d_ws, size_t ws_size,
                              hipStream_t stream)
{
    const float* pred   = (const float*)d_in[0];
    const float* target = (const float*)d_in[1];

    float* ws_sq  = (float*)((char*)d_ws + WS_SQ_OFF);
    float* ws_cos = (float*)((char*)d_ws + WS_COS_OFF);

    const size_t map_bytes = (size_t)BB * HW * sizeof(__half);   // 8 MB per map
    const size_t need = WS_MAP_OFF + 3 * map_bytes;

    if (ws_size >= need) {
        __half2* hdot = (__half2*)((char*)d_ws + WS_MAP_OFF);
        __half2* hpp  = (__half2*)((char*)d_ws + WS_MAP_OFF + map_bytes);
        __half2* htt  = (__half2*)((char*)d_ws + WS_MAP_OFF + 2 * map_bytes);
        k1_hpass<<<dim3(BB * HH / 4), 256, 0, stream>>>(pred, target, hdot, hpp, htt, ws_sq);
        k2_vpass<<<dim3(BB * (HH / SEG)), 256, 0, stream>>>(hdot, hpp, htt, ws_cos);
        finalize2<<<1, 256, 0, stream>>>(ws_sq, ws_cos, (float*)d_out);
    } else {
        dim3 grid(WW / TS, HH / TS, BB);
        psnr_lcs_fused<<<grid, 256, 0, stream>>>(pred, target, ws_sq, ws_cos);
        finalize_fb<<<1, 256, 0, stream>>>(ws_sq, ws_cos, (float*)d_out);
    }
}

// Round 4
// 41.912 us; speedup vs baseline: 3.4612x; 1.1050x over previous
//
#include <hip/hip_runtime.h>
#include <hip/hip_fp16.h>
#include <math.h>

#define BB 16
#define CC 3
#define HH 512
#define WW 512
#define HW (HH * WW)
#define KW 11
#define RAD 5

// ws layout: [0, 8KB) ws_sq (2048 f), [8KB, 12KB) ws_cos (1024 f), maps from 16KB
#define WS_SQ_OFF   0
#define WS_COS_OFF  8192
#define WS_MAP_OFF  16384

union H2F { __half2 h; float f; };

// ---------------- Kernel 1: horizontal pass (one wave per row) ----------------
#define SIDX(s) ((s) + ((s) >> 3))
#define SBUF 592

__global__ __launch_bounds__(256) void k1_hpass(
    const float* __restrict__ pred, const float* __restrict__ target,
    __half2* __restrict__ hdot, __half2* __restrict__ hpp, __half2* __restrict__ htt,
    float* __restrict__ ws_sq)
{
    __shared__ float sbuf[4][3][SBUF];
    __shared__ float red[4];
    const int tid = threadIdx.x;
    const int wave = tid >> 6, lane = tid & 63;
    const int row = blockIdx.x * 4 + wave;      // 0..8191, 128 blocks per image
    const int b = row >> 9, y = row & 511;
    const long rbase = (long)b * (CC * HW) + (long)y * WW;
    const int c0 = lane * 8;

    float p[3][8], t[3][8];
    #pragma unroll
    for (int ch = 0; ch < 3; ++ch) {
        const float* pp_ = pred + rbase + (long)ch * HW + c0;
        const float* tp_ = target + rbase + (long)ch * HW + c0;
        float4 a0 = *(const float4*)pp_;
        float4 a1 = *(const float4*)(pp_ + 4);
        float4 b0 = *(const float4*)tp_;
        float4 b1 = *(const float4*)(tp_ + 4);
        p[ch][0]=a0.x; p[ch][1]=a0.y; p[ch][2]=a0.z; p[ch][3]=a0.w;
        p[ch][4]=a1.x; p[ch][5]=a1.y; p[ch][6]=a1.z; p[ch][7]=a1.w;
        t[ch][0]=b0.x; t[ch][1]=b0.y; t[ch][2]=b0.z; t[ch][3]=b0.w;
        t[ch][4]=b1.x; t[ch][5]=b1.y; t[ch][6]=b1.z; t[ch][7]=b1.w;
    }

    float sq = 0.f;
    #pragma unroll
    for (int j = 0; j < 8; ++j) {
        const float dot = p[0][j]*t[0][j] + p[1][j]*t[1][j] + p[2][j]*t[2][j];
        const float pps = p[0][j]*p[0][j] + p[1][j]*p[1][j] + p[2][j]*p[2][j];
        const float tts = t[0][j]*t[0][j] + t[1][j]*t[1][j] + t[2][j]*t[2][j];
        const float e0 = p[0][j]-t[0][j], e1 = p[1][j]-t[1][j], e2 = p[2][j]-t[2][j];
        sq += e0*e0 + e1*e1 + e2*e2;
        const int idx = SIDX(c0 + j + RAD);
        sbuf[wave][0][idx] = dot;
        sbuf[wave][1][idx] = pps;
        sbuf[wave][2][idx] = tts;
    }
    if (lane < 5) {
        const int i0 = SIDX(lane);
        sbuf[wave][0][i0] = 0.f; sbuf[wave][1][i0] = 0.f; sbuf[wave][2][i0] = 0.f;
    } else if (lane < 10) {
        const int i1 = SIDX(512 + lane);
        sbuf[wave][0][i1] = 0.f; sbuf[wave][1][i1] = 0.f; sbuf[wave][2][i1] = 0.f;
    }
    __syncthreads();

    float vd[18], vp[18], vt[18];
    #pragma unroll
    for (int k = 0; k < 18; ++k) {
        const int idx = SIDX(c0 + k);
        vd[k] = sbuf[wave][0][idx];
        vp[k] = sbuf[wave][1][idx];
        vt[k] = sbuf[wave][2][idx];
    }
    float wd[8], wp[8], wt[8];
    wd[0] = vd[0]; wp[0] = vp[0]; wt[0] = vt[0];
    #pragma unroll
    for (int k = 1; k < 11; ++k) { wd[0]+=vd[k]; wp[0]+=vp[k]; wt[0]+=vt[k]; }
    #pragma unroll
    for (int j = 1; j < 8; ++j) {
        wd[j] = wd[j-1] + vd[j+10] - vd[j-1];
        wp[j] = wp[j-1] + vp[j+10] - vp[j-1];
        wt[j] = wt[j-1] + vt[j+10] - vt[j-1];
    }

    const long obase = (long)row * (WW/2) + lane * 4;   // half2 units
    float4 od, op, ot;
    { H2F u; u.h = __floats2half2_rn(wd[0], wd[1]); od.x = u.f;
      u.h = __floats2half2_rn(wd[2], wd[3]); od.y = u.f;
      u.h = __floats2half2_rn(wd[4], wd[5]); od.z = u.f;
      u.h = __floats2half2_rn(wd[6], wd[7]); od.w = u.f; }
    { H2F u; u.h = __floats2half2_rn(wp[0], wp[1]); op.x = u.f;
      u.h = __floats2half2_rn(wp[2], wp[3]); op.y = u.f;
      u.h = __floats2half2_rn(wp[4], wp[5]); op.z = u.f;
      u.h = __floats2half2_rn(wp[6], wp[7]); op.w = u.f; }
    { H2F u; u.h = __floats2half2_rn(wt[0], wt[1]); ot.x = u.f;
      u.h = __floats2half2_rn(wt[2], wt[3]); ot.y = u.f;
      u.h = __floats2half2_rn(wt[4], wt[5]); ot.z = u.f;
      u.h = __floats2half2_rn(wt[6], wt[7]); ot.w = u.f; }
    *(float4*)&hdot[obase] = od;
    *(float4*)&hpp [obase] = op;
    *(float4*)&htt [obase] = ot;

    #pragma unroll
    for (int o = 32; o > 0; o >>= 1) sq += __shfl_down(sq, o);
    if (lane == 0) red[wave] = sq;
    __syncthreads();
    if (tid == 0)
        ws_sq[blockIdx.x] = red[0] + red[1] + red[2] + red[3];
}

// ---------------- Kernel 2: vertical pass + cosine ----------------
// SEG=8 -> 64 segments/image, 1024 blocks (4 blocks/CU, 16 waves/CU).
// Interior segments (1..62): unconditional loads -> deep compiler pipelining.
#define SEG 8
#define NSEG (HH / SEG)     // 64

__global__ __launch_bounds__(256) void k2_vpass(
    const __half2* __restrict__ hdot, const __half2* __restrict__ hpp,
    const __half2* __restrict__ htt, float* __restrict__ ws_cos)
{
    __shared__ float red[4];
    const int tid = threadIdx.x;
    const int b = blockIdx.x >> 6;          // /NSEG
    const int seg = blockIdx.x & (NSEG - 1);
    const int y0 = seg * SEG;
    const long plane = (long)b * (HW / 2);

    float2 rd[11], rp[11], rt[11];
    float cosacc = 0.f;

    if (seg >= 1 && seg <= NSEG - 2) {
        // interior: rows y0-5 .. y0+12 all valid
        const long rowbase = plane + (long)(y0 - RAD) * (WW/2) + tid;
        #pragma unroll
        for (int it = 0; it < SEG + 10; ++it) {
            const long off = rowbase + (long)it * (WW/2);
            float2 d  = __half22float2(hdot[off]);
            float2 pq = __half22float2(hpp[off]);
            float2 tq = __half22float2(htt[off]);
            rd[it % 11] = d; rp[it % 11] = pq; rt[it % 11] = tq;
            if (it >= 10) {
                float2 sd = rd[0], sp = rp[0], st = rt[0];
                #pragma unroll
                for (int k = 1; k < 11; ++k) {
                    sd.x += rd[k].x; sd.y += rd[k].y;
                    sp.x += rp[k].x; sp.y += rp[k].y;
                    st.x += rt[k].x; st.y += rt[k].y;
                }
                cosacc += sd.x / (sqrtf(sp.x) * sqrtf(st.x) + 1e-6f);
                cosacc += sd.y / (sqrtf(sp.y) * sqrtf(st.y) + 1e-6f);
            }
        }
    } else {
        // edge: clamp row, multiply-mask (loads stay unconditional)
        #pragma unroll
        for (int it = 0; it < SEG + 10; ++it) {
            const int y = y0 - RAD + it;
            const int yc = min(max(y, 0), HH - 1);
            const float m = (y >= 0 && y < HH) ? 1.f : 0.f;
            const long off = plane + (long)yc * (WW/2) + tid;
            float2 d  = __half22float2(hdot[off]);
            float2 pq = __half22float2(hpp[off]);
            float2 tq = __half22float2(htt[off]);
            d.x *= m; d.y *= m; pq.x *= m; pq.y *= m; tq.x *= m; tq.y *= m;
            rd[it % 11] = d; rp[it % 11] = pq; rt[it % 11] = tq;
            if (it >= 10) {
                float2 sd = rd[0], sp = rp[0], st = rt[0];
                #pragma unroll
                for (int k = 1; k < 11; ++k) {
                    sd.x += rd[k].x; sd.y += rd[k].y;
                    sp.x += rp[k].x; sp.y += rp[k].y;
                    st.x += rt[k].x; st.y += rt[k].y;
                }
                cosacc += sd.x / (sqrtf(sp.x) * sqrtf(st.x) + 1e-6f);
                cosacc += sd.y / (sqrtf(sp.y) * sqrtf(st.y) + 1e-6f);
            }
        }
    }

    #pragma unroll
    for (int o = 32; o > 0; o >>= 1) cosacc += __shfl_down(cosacc, o);
    const int wave = tid >> 6, lane = tid & 63;
    if (lane == 0) red[wave] = cosacc;
    __syncthreads();
    if (tid == 0)
        ws_cos[blockIdx.x] = red[0] + red[1] + red[2] + red[3];
}

// ---------------- finalize: reduce 2048 sq-partials + 1024 cos-partials ----------------
__global__ __launch_bounds__(256) void finalize2(
    const float* __restrict__ ws_sq, const float* __restrict__ ws_cos,
    float* __restrict__ out)
{
    __shared__ float sq_b[16];
    __shared__ float cred[4];
    const int tid = threadIdx.x;

    const int b = tid >> 4, j = tid & 15;
    float s = 0.f;
    #pragma unroll
    for (int k = 0; k < 8; ++k) s += ws_sq[b * 128 + j * 8 + k];
    #pragma unroll
    for (int o = 8; o > 0; o >>= 1) s += __shfl_down(s, o, 16);
    if (j == 0) sq_b[b] = s;

    float c = ws_cos[tid] + ws_cos[tid + 256] + ws_cos[tid + 512] + ws_cos[tid + 768];
    #pragma unroll
    for (int o = 32; o > 0; o >>= 1) c += __shfl_down(c, o);
    if ((tid & 63) == 0) cred[tid >> 6] = c;
    __syncthreads();

    if (tid == 0) {
        const float csum = cred[0] + cred[1] + cred[2] + cred[3];
        const float scale = 4.342944819032518f;   // 10 / ln(10)
        float lsum = 0.f;
        for (int bb = 0; bb < 16; ++bb)
            lsum += logf(sq_b[bb] / (float)(CC * HW) + 1e-8f);
        out[0] = scale * (lsum / (float)BB) + (1.f - csum / (float)(BB * HW));
    }
}

// ---------------- fallback fused kernel (small ws): per-block partial stores ----------------
#define TS 32
#define RS (TS + KW - 1)
__global__ __launch_bounds__(256) void psnr_lcs_fused(
    const float* __restrict__ pred, const float* __restrict__ target,
    float* __restrict__ ws_sq, float* __restrict__ ws_cos)
{
    __shared__ float s_dot[RS][RS], s_pp[RS][RS], s_tt[RS][RS];
    __shared__ float h_dot[RS][TS], h_pp[RS][TS], h_tt[RS][TS];
    __shared__ float red[8];
    const int tid = threadIdx.x;
    const int bx = blockIdx.x, by = blockIdx.y, b = blockIdx.z;
    const long base = (long)b * CC * HW;
    for (int idx = tid; idx < RS * RS; idx += 256) {
        const int rr = idx / RS, cc = idx % RS;
        const int gy = by * TS + rr - RAD, gx = bx * TS + cc - RAD;
        float dot = 0.f, pp = 0.f, tt = 0.f;
        if (gx >= 0 && gx < WW && gy >= 0 && gy < HH) {
            const long off = base + (long)gy * WW + gx;
            const float p0 = pred[off], t0 = target[off];
            const float p1 = pred[off+HW], t1 = target[off+HW];
            const float p2 = pred[off+2*HW], t2 = target[off+2*HW];
            dot = p0*t0+p1*t1+p2*t2; pp = p0*p0+p1*p1+p2*p2; tt = t0*t0+t1*t1+t2*t2;
        }
        s_dot[rr][cc]=dot; s_pp[rr][cc]=pp; s_tt[rr][cc]=tt;
    }
    __syncthreads();
    for (int idx = tid; idx < RS * TS; idx += 256) {
        const int r = idx / TS, c = idx % TS;
        float sd=0.f, sp=0.f, st=0.f;
        #pragma unroll
        for (int dx = 0; dx < KW; ++dx) { sd+=s_dot[r][c+dx]; sp+=s_pp[r][c+dx]; st+=s_tt[r][c+dx]; }
        h_dot[r][c]=sd; h_pp[r][c]=sp; h_tt[r][c]=st;
    }
    __syncthreads();
    float cos_part = 0.f, sq_part = 0.f;
    const int oc = tid & 31, r0 = tid >> 5;
    #pragma unroll
    for (int k = 0; k < 4; ++k) {
        const int orow = r0 + k * 8;
        float sxy=0.f, sxx=0.f, syy=0.f;
        #pragma unroll
        for (int dy = 0; dy < KW; ++dy) { sxy+=h_dot[orow+dy][oc]; sxx+=h_pp[orow+dy][oc]; syy+=h_tt[orow+dy][oc]; }
        cos_part += sxy / (sqrtf(sxx)*sqrtf(syy) + 1e-6f);
        sq_part += s_pp[orow+RAD][oc+RAD] - 2.f*s_dot[orow+RAD][oc+RAD] + s_tt[orow+RAD][oc+RAD];
    }
    #pragma unroll
    for (int o = 32; o > 0; o >>= 1) { cos_part += __shfl_down(cos_part, o); sq_part += __shfl_down(sq_part, o); }
    const int wave = tid >> 6, lane = tid & 63;
    if (lane == 0) { red[wave] = cos_part; red[wave+4] = sq_part; }
    __syncthreads();
    if (tid == 0) {
        const int flat = (b * gridDim.y + by) * gridDim.x + bx;   // 0..4095
        ws_sq[flat]  = red[4]+red[5]+red[6]+red[7];
        ws_cos[flat] = red[0]+red[1]+red[2]+red[3];
    }
}

__global__ __launch_bounds__(256) void finalize_fb(
    const float* __restrict__ ws_sq, const float* __restrict__ ws_cos,
    float* __restrict__ out)
{
    __shared__ float sq_b[16];
    __shared__ float cred[4];
    const int tid = threadIdx.x;
    const int b = tid >> 4, j = tid & 15;
    float s = 0.f, c = 0.f;
    #pragma unroll
    for (int k = 0; k < 16; ++k) {
        s += ws_sq[b * 256 + j * 16 + k];
        c += ws_cos[b * 256 + j * 16 + k];
    }
    #pragma unroll
    for (int o = 8; o > 0; o >>= 1) s += __shfl_down(s, o, 16);
    if (j == 0) sq_b[b] = s;
    #pragma unroll
    for (int o = 32; o > 0; o >>= 1) c += __shfl_down(c, o);
    if ((tid & 63) == 0) cred[tid >> 6] = c;
    __syncthreads();
    if (tid == 0) {
        const float csum = cred[0] + cred[1] + cred[2] + cred[3];
        const float scale = 4.342944819032518f;
        float lsum = 0.f;
        for (int bb = 0; bb < 16; ++bb)
            lsum += logf(sq_b[bb] / (float)(CC * HW) + 1e-8f);
        out[0] = scale * (lsum / (float)BB) + (1.f - csum / (float)(BB * HW));
    }
}

extern "C" void kernel_launch(void* const* d_in, const int* in_sizes, int n_in,
                              void* d_out, int out_size, void* d_ws, size_t ws_size,
                              hipStream_t stream)
{
    const float* pred   = (const float*)d_in[0];
    const float* target = (const float*)d_in[1];

    float* ws_sq  = (float*)((char*)d_ws + WS_SQ_OFF);
    float* ws_cos = (float*)((char*)d_ws + WS_COS_OFF);

    const size_t map_bytes = (size_t)BB * HW * sizeof(__half);   // 8 MB per map
    const size_t need = WS_MAP_OFF + 3 * map_bytes;

    if (ws_size >= need) {
        __half2* hdot = (__half2*)((char*)d_ws + WS_MAP_OFF);
        __half2* hpp  = (__half2*)((char*)d_ws + WS_MAP_OFF + map_bytes);
        __half2* htt  = (__half2*)((char*)d_ws + WS_MAP_OFF + 2 * map_bytes);
        k1_hpass<<<dim3(BB * HH / 4), 256, 0, stream>>>(pred, target, hdot, hpp, htt, ws_sq);
        k2_vpass<<<dim3(BB * NSEG), 256, 0, stream>>>(hdot, hpp, htt, ws_cos);
        finalize2<<<1, 256, 0, stream>>>(ws_sq, ws_cos, (float*)d_out);
    } else {
        dim3 grid(WW / TS, HH / TS, BB);
        psnr_lcs_fused<<<grid, 256, 0, stream>>>(pred, target, ws_sq, ws_cos);
        finalize_fb<<<1, 256, 0, stream>>>(ws_sq, ws_cos, (float*)d_out);
    }
}